// Round 1
// baseline (525.590 us; speedup 1.0000x reference)
//
#include <hip/hip_runtime.h>
#include <math.h>

// Problem constants
#define BATCH 8192
#define NB 9
#define NN 256
#define PMAX 8
#define HID 32
#define ZDIM 2304   // NB*NN

// -------------------- K0a: pack gW1T[k][h][j] = gW1[k][j][h] --------------------
__global__ __launch_bounds__(256) void k_pack_gw1t(const float* __restrict__ gW1,
                                                   float* __restrict__ gW1T) {
    int idx = blockIdx.x * 256 + threadIdx.x;      // 9*32*256 = 73728
    int j = idx & 255;
    int h = (idx >> 8) & 31;
    int k = idx >> 13;
    gW1T[idx] = gW1[(k * 256 + j) * 32 + h];
}

// -------------------- K0b: WT[r][j][i] = W[r][i][j] --------------------
__global__ __launch_bounds__(256) void k_transpose_w(const float* __restrict__ W,
                                                     float* __restrict__ WT) {
    __shared__ float t[32][33];
    int r = blockIdx.z;
    int i0 = blockIdx.y * 32;
    int j0 = blockIdx.x * 32;
    int tx = threadIdx.x & 31;
    int ty = threadIdx.x >> 5;                     // 0..7
    const float* src = W + (size_t)r * 65536;
    #pragma unroll
    for (int s = 0; s < 32; s += 8)
        t[ty + s][tx] = src[(size_t)(i0 + ty + s) * 256 + (j0 + tx)];
    __syncthreads();
    float* dst = WT + (size_t)r * 65536;
    #pragma unroll
    for (int s = 0; s < 32; s += 8)
        dst[(size_t)(j0 + ty + s) * 256 + (i0 + tx)] = t[tx][ty + s];
}

// -------------------- K1: d1[k][b][h] (post-activation-grad at layer 1) ---------
// One 32-lane half-wave handles 4 consecutive batch rows of one block k.
__global__ __launch_bounds__(256) void k_mlp_d1(
    const float* __restrict__ z, const float* __restrict__ gW1,
    const float* __restrict__ gb1, const float* __restrict__ gW2,
    const float* __restrict__ gb2, const float* __restrict__ gW3,
    float* __restrict__ d1ws) {
    int tid = threadIdx.x;
    int lane = tid & 31;
    int p = blockIdx.x * 8 + (tid >> 5);           // 0..18431 = 9 * 2048
    int k = p >> 11;
    int b0 = (p & 2047) * 4;

    const float* w1 = gW1 + (size_t)k * 8192;      // [n][h], 256x32
    const float* w2 = gW2 + (size_t)k * 1024;      // [h][g], 32x32
    const float* x  = z + (size_t)b0 * ZDIM + k * NN;

    float a1[4];
    float bias1 = gb1[k * 32 + lane];
    #pragma unroll
    for (int r = 0; r < 4; ++r) a1[r] = bias1;

    for (int n = 0; n < 256; ++n) {
        float w = w1[n * 32 + lane];
        #pragma unroll
        for (int r = 0; r < 4; ++r) a1[r] += x[(size_t)r * ZDIM + n] * w;
    }
    float s1[4], h1v[4];
    #pragma unroll
    for (int r = 0; r < 4; ++r) {
        s1[r]  = 1.f / (1.f + __expf(-a1[r]));
        h1v[r] = a1[r] * s1[r];
    }
    float a2[4];
    float bias2 = gb2[k * 32 + lane];
    #pragma unroll
    for (int r = 0; r < 4; ++r) a2[r] = bias2;
    #pragma unroll 8
    for (int h = 0; h < 32; ++h) {
        float w = w2[h * 32 + lane];
        #pragma unroll
        for (int r = 0; r < 4; ++r) a2[r] += __shfl(h1v[r], h, 32) * w;
    }
    float g3 = gW3[k * 32 + lane];
    float da2[4];
    #pragma unroll
    for (int r = 0; r < 4; ++r) {
        float s2 = 1.f / (1.f + __expf(-a2[r]));
        da2[r] = g3 * s2 * (1.f + a2[r] * (1.f - s2));   // gW3 * silu'(a2)
    }
    float dh1[4] = {0.f, 0.f, 0.f, 0.f};
    #pragma unroll 8
    for (int g = 0; g < 32; ++g) {
        float w = w2[lane * 32 + g];
        #pragma unroll
        for (int r = 0; r < 4; ++r) dh1[r] += __shfl(da2[r], g, 32) * w;
    }
    float* o = d1ws + ((size_t)k * BATCH + b0) * 32 + lane;
    #pragma unroll
    for (int r = 0; r < 4; ++r) {
        float da1 = dh1[r] * s1[r] * (1.f + a1[r] * (1.f - s1[r]));  // silu'(a1)
        o[r * 32] = da1;
    }
}

// -------------------- K2: out[:, 0:2048] = -(z8 @ W[7-k]  +  d1_k @ gW1[k]^T) ---
// M=8192, N=2048, K=256 (+32 ext). 128x128 tile, 8x8 micro-tile, KT=16.
__global__ __launch_bounds__(256) void k_gemm_lo(
    const float* __restrict__ z, const float* __restrict__ W,
    const float* __restrict__ gW1T, const float* __restrict__ d1ws,
    float* __restrict__ out) {
    __shared__ float As[16][128];
    __shared__ float Bs[16][132];                  // +4 pad
    int t = threadIdx.x;
    int b0 = blockIdx.y * 128;
    int n0 = blockIdx.x * 128;                     // 0..1920
    int k  = n0 >> 8;                              // 0..7
    int jb = n0 & 255;                             // 0 or 128

    const float* Az = z + (size_t)b0 * ZDIM + 2048;
    const float* Wk = W + (size_t)(7 - k) * 65536 + jb;
    const float* AE = d1ws + ((size_t)k * BATCH + b0) * 32;
    const float* BE = gW1T + (size_t)k * 8192 + jb;

    int am = t >> 2, af = t & 3;                   // A loader: row, k-quad
    int bi = t >> 5, bj = (t & 31) * 4;            // B loader: row, col
    int tx = t & 15, ty = t >> 4;                  // compute grid

    float acc[8][8];
    #pragma unroll
    for (int i = 0; i < 8; ++i)
        #pragma unroll
        for (int j = 0; j < 8; ++j) acc[i][j] = 0.f;

    for (int c = 0; c < 18; ++c) {
        float4 a0, a1, bv0, bv1;
        if (c < 16) {
            int kc = c * 16;
            a0  = *(const float4*)(Az + (size_t)am * ZDIM + kc + af * 4);
            a1  = *(const float4*)(Az + (size_t)(am + 64) * ZDIM + kc + af * 4);
            bv0 = *(const float4*)(Wk + (size_t)(kc + bi) * 256 + bj);
            bv1 = *(const float4*)(Wk + (size_t)(kc + bi + 8) * 256 + bj);
        } else {
            int h0 = (c - 16) * 16;
            a0  = *(const float4*)(AE + (size_t)am * 32 + h0 + af * 4);
            a1  = *(const float4*)(AE + (size_t)(am + 64) * 32 + h0 + af * 4);
            bv0 = *(const float4*)(BE + (size_t)(h0 + bi) * 256 + bj);
            bv1 = *(const float4*)(BE + (size_t)(h0 + bi + 8) * 256 + bj);
        }
        __syncthreads();
        As[af * 4 + 0][am] = a0.x; As[af * 4 + 1][am] = a0.y;
        As[af * 4 + 2][am] = a0.z; As[af * 4 + 3][am] = a0.w;
        As[af * 4 + 0][am + 64] = a1.x; As[af * 4 + 1][am + 64] = a1.y;
        As[af * 4 + 2][am + 64] = a1.z; As[af * 4 + 3][am + 64] = a1.w;
        *(float4*)&Bs[bi][bj]     = bv0;
        *(float4*)&Bs[bi + 8][bj] = bv1;
        __syncthreads();
        #pragma unroll
        for (int kk = 0; kk < 16; ++kk) {
            float a[8], b[8];
            *(float4*)&a[0] = *(const float4*)&As[kk][ty * 8];
            *(float4*)&a[4] = *(const float4*)&As[kk][ty * 8 + 4];
            *(float4*)&b[0] = *(const float4*)&Bs[kk][tx * 8];
            *(float4*)&b[4] = *(const float4*)&Bs[kk][tx * 8 + 4];
            #pragma unroll
            for (int i = 0; i < 8; ++i)
                #pragma unroll
                for (int j = 0; j < 8; ++j)
                    acc[i][j] += a[i] * b[j];
        }
    }
    float* o = out + (size_t)b0 * ZDIM + k * 256 + jb;
    #pragma unroll
    for (int i = 0; i < 8; ++i) {
        float4 v0 = make_float4(-acc[i][0], -acc[i][1], -acc[i][2], -acc[i][3]);
        float4 v1 = make_float4(-acc[i][4], -acc[i][5], -acc[i][6], -acc[i][7]);
        *(float4*)(o + (size_t)(ty * 8 + i) * ZDIM + tx * 8)     = v0;
        *(float4*)(o + (size_t)(ty * 8 + i) * ZDIM + tx * 8 + 4) = v1;
    }
}

// ---- K3: out[:, 2048:2304] = -(Σ_m x_m @ W[7-m]^T + d1_8 @ gW1[8]^T) ----------
// M=8192, N=256, K=2048 (+32 ext). 128x64 tile, 8x4 micro-tile, KT=16.
__global__ __launch_bounds__(256) void k_gemm_hi(
    const float* __restrict__ z, const float* __restrict__ WT,
    const float* __restrict__ gW1T, const float* __restrict__ d1ws,
    float* __restrict__ out) {
    __shared__ float As[16][128];
    __shared__ float Bs[16][68];                   // +4 pad
    int t = threadIdx.x;
    int b0 = blockIdx.y * 128;
    int i0 = blockIdx.x * 64;

    const float* Az = z + (size_t)b0 * ZDIM;
    const float* AE = d1ws + ((size_t)8 * BATCH + b0) * 32;
    const float* BE = gW1T + (size_t)8 * 8192;

    int am = t >> 2, af = t & 3;
    int bi = t >> 4, bj = (t & 15) * 4;            // B loader: 16 rows x 64 cols
    int tx = t & 15, ty = t >> 4;

    float acc[8][4];
    #pragma unroll
    for (int i = 0; i < 8; ++i)
        #pragma unroll
        for (int j = 0; j < 4; ++j) acc[i][j] = 0.f;

    for (int c = 0; c < 130; ++c) {
        float4 a0, a1, bv;
        if (c < 128) {
            int kc = c * 16;
            a0 = *(const float4*)(Az + (size_t)am * ZDIM + kc + af * 4);
            a1 = *(const float4*)(Az + (size_t)(am + 64) * ZDIM + kc + af * 4);
            int m  = c >> 4;                       // lag block of this K-chunk
            int jj = (kc & 255) + bi;
            bv = *(const float4*)(WT + (size_t)(7 - m) * 65536 + (size_t)jj * 256 + i0 + bj);
        } else {
            int h0 = (c - 128) * 16;
            a0 = *(const float4*)(AE + (size_t)am * 32 + h0 + af * 4);
            a1 = *(const float4*)(AE + (size_t)(am + 64) * 32 + h0 + af * 4);
            bv = *(const float4*)(BE + (size_t)(h0 + bi) * 256 + i0 + bj);
        }
        __syncthreads();
        As[af * 4 + 0][am] = a0.x; As[af * 4 + 1][am] = a0.y;
        As[af * 4 + 2][am] = a0.z; As[af * 4 + 3][am] = a0.w;
        As[af * 4 + 0][am + 64] = a1.x; As[af * 4 + 1][am + 64] = a1.y;
        As[af * 4 + 2][am + 64] = a1.z; As[af * 4 + 3][am + 64] = a1.w;
        *(float4*)&Bs[bi][bj] = bv;
        __syncthreads();
        #pragma unroll
        for (int kk = 0; kk < 16; ++kk) {
            float a[8], b[4];
            *(float4*)&a[0] = *(const float4*)&As[kk][ty * 8];
            *(float4*)&a[4] = *(const float4*)&As[kk][ty * 8 + 4];
            *(float4*)&b[0] = *(const float4*)&Bs[kk][tx * 4];
            #pragma unroll
            for (int i = 0; i < 8; ++i)
                #pragma unroll
                for (int j = 0; j < 4; ++j)
                    acc[i][j] += a[i] * b[j];
        }
    }
    float* o = out + (size_t)b0 * ZDIM + 2048 + i0;
    #pragma unroll
    for (int i = 0; i < 8; ++i) {
        float4 v = make_float4(-acc[i][0], -acc[i][1], -acc[i][2], -acc[i][3]);
        *(float4*)(o + (size_t)(ty * 8 + i) * ZDIM + tx * 4) = v;
    }
}

extern "C" void kernel_launch(void* const* d_in, const int* in_sizes, int n_in,
                              void* d_out, int out_size, void* d_ws, size_t ws_size,
                              hipStream_t stream) {
    const float* z   = (const float*)d_in[0];
    const float* gW1 = (const float*)d_in[1];
    const float* gb1 = (const float*)d_in[2];
    const float* gW2 = (const float*)d_in[3];
    const float* gb2 = (const float*)d_in[4];
    const float* gW3 = (const float*)d_in[5];
    // d_in[6] = gb3: constant offset, no gradient contribution
    const float* W   = (const float*)d_in[7];
    float* out = (float*)d_out;

    float* ws    = (float*)d_ws;
    float* d1ws  = ws;                   // [9][8192][32]  = 2359296 floats
    float* gW1T  = ws + 2359296;         // [9][32][256]   = 73728 floats
    float* WTp   = gW1T + 73728;         // [8][256][256]  = 524288 floats (~11.3 MB total)

    k_pack_gw1t<<<288, 256, 0, stream>>>(gW1, gW1T);
    k_transpose_w<<<dim3(8, 8, 8), 256, 0, stream>>>(W, WTp);
    k_mlp_d1<<<2304, 256, 0, stream>>>(z, gW1, gb1, gW2, gb2, gW3, d1ws);
    k_gemm_lo<<<dim3(16, 64), 256, 0, stream>>>(z, W, gW1T, d1ws, out);
    k_gemm_hi<<<dim3(4, 64), 256, 0, stream>>>(z, WTp, gW1T, d1ws, out);
}

// Round 2
// 355.373 us; speedup vs baseline: 1.4790x; 1.4790x over previous
//
#include <hip/hip_runtime.h>
#include <hip/hip_bf16.h>
#include <math.h>

// Problem constants
#define BATCH 8192
#define NB 9
#define NN 256
#define PMAX 8
#define HID 32
#define ZDIM 2304   // NB*NN

typedef short bf16x8 __attribute__((ext_vector_type(8)));   // 8 bf16 in 4 VGPRs
typedef float f32x4 __attribute__((ext_vector_type(4)));    // MFMA accumulator

static __device__ inline unsigned short f2bf(float f) {
    __hip_bfloat16 h = __float2bfloat16(f);
    return *reinterpret_cast<unsigned short*>(&h);
}

static __device__ inline uint4 pack8(float4 a, float4 b) {
    uint4 u;
    u.x = (unsigned)f2bf(a.x) | ((unsigned)f2bf(a.y) << 16);
    u.y = (unsigned)f2bf(a.z) | ((unsigned)f2bf(a.w) << 16);
    u.z = (unsigned)f2bf(b.x) | ((unsigned)f2bf(b.y) << 16);
    u.w = (unsigned)f2bf(b.z) | ((unsigned)f2bf(b.w) << 16);
    return u;
}

// ---------------- K0: pack weights to bf16 (+ fp32 gW1 transpose for mlp) ------
// z<8: W[r] 32x32 tiles -> Wb natural bf16, WTb transposed bf16.
// z==8: gW1 -> gW1b (bf16 natural [k][n][h]) and g1T (fp32 [k][h][n]).
__global__ __launch_bounds__(256) void k_pack(
    const float* __restrict__ W, const float* __restrict__ gW1,
    unsigned short* __restrict__ Wb, unsigned short* __restrict__ WTb,
    unsigned short* __restrict__ gW1b, float* __restrict__ g1T) {
    int r = blockIdx.z;
    int t = threadIdx.x;
    if (r < 8) {
        __shared__ float tt[32][33];
        int i0 = blockIdx.y * 32;
        int j0 = blockIdx.x * 32;
        int tx = t & 31;
        int ty = t >> 5;
        const float* src = W + (size_t)r * 65536;
        #pragma unroll
        for (int s = 0; s < 32; s += 8) {
            float v = src[(size_t)(i0 + ty + s) * 256 + (j0 + tx)];
            tt[ty + s][tx] = v;
            Wb[(size_t)r * 65536 + (size_t)(i0 + ty + s) * 256 + (j0 + tx)] = f2bf(v);
        }
        __syncthreads();
        #pragma unroll
        for (int s = 0; s < 32; s += 8)
            WTb[(size_t)r * 65536 + (size_t)(j0 + ty + s) * 256 + (i0 + tx)] = f2bf(tt[tx][ty + s]);
    } else {
        int tg = (blockIdx.y * 8 + blockIdx.x) * 256 + t;       // 0..16383
        for (int e = tg; e < 73728; e += 16384) {
            float v = gW1[e];
            gW1b[e] = f2bf(v);
            int k = e >> 13, n = (e >> 5) & 255, h = e & 31;
            g1T[(size_t)(k * 32 + h) * 256 + n] = v;
        }
    }
}

// -------------------- K1: d1[k][b][h] = silu'(a1) * upstream (fp32) ------------
__global__ __launch_bounds__(256) void k_mlp_d1(
    const float* __restrict__ z, const float* __restrict__ g1T,
    const float* __restrict__ gb1, const float* __restrict__ gW2,
    const float* __restrict__ gb2, const float* __restrict__ gW3,
    float* __restrict__ d1ws) {
    int tid = threadIdx.x;
    int lane = tid & 31;
    int p = blockIdx.x * 8 + (tid >> 5);           // 0..18431 = 9 * 2048
    int k = p >> 11;
    int b0 = (p & 2047) * 4;

    const float* w1t = g1T + (size_t)k * 8192 + (size_t)lane * 256;  // [h=lane][n]
    const float* w2  = gW2 + (size_t)k * 1024;                       // [h][g]
    const float* x   = z + (size_t)b0 * ZDIM + k * NN;

    float a1[4];
    float bias1 = gb1[k * 32 + lane];
    #pragma unroll
    for (int r = 0; r < 4; ++r) a1[r] = bias1;

    for (int n4 = 0; n4 < 64; ++n4) {
        float4 wv = *(const float4*)(w1t + n4 * 4);
        float4 x0 = *(const float4*)(x + n4 * 4);
        float4 x1 = *(const float4*)(x + ZDIM + n4 * 4);
        float4 x2 = *(const float4*)(x + 2 * ZDIM + n4 * 4);
        float4 x3 = *(const float4*)(x + 3 * ZDIM + n4 * 4);
        a1[0] += x0.x * wv.x + x0.y * wv.y + x0.z * wv.z + x0.w * wv.w;
        a1[1] += x1.x * wv.x + x1.y * wv.y + x1.z * wv.z + x1.w * wv.w;
        a1[2] += x2.x * wv.x + x2.y * wv.y + x2.z * wv.z + x2.w * wv.w;
        a1[3] += x3.x * wv.x + x3.y * wv.y + x3.z * wv.z + x3.w * wv.w;
    }
    float s1[4], h1v[4];
    #pragma unroll
    for (int r = 0; r < 4; ++r) {
        s1[r]  = 1.f / (1.f + __expf(-a1[r]));
        h1v[r] = a1[r] * s1[r];
    }
    float a2[4];
    float bias2 = gb2[k * 32 + lane];
    #pragma unroll
    for (int r = 0; r < 4; ++r) a2[r] = bias2;
    #pragma unroll 8
    for (int h = 0; h < 32; ++h) {
        float w = w2[h * 32 + lane];
        #pragma unroll
        for (int r = 0; r < 4; ++r) a2[r] += __shfl(h1v[r], h, 32) * w;
    }
    float g3 = gW3[k * 32 + lane];
    float da2[4];
    #pragma unroll
    for (int r = 0; r < 4; ++r) {
        float s2 = 1.f / (1.f + __expf(-a2[r]));
        da2[r] = g3 * s2 * (1.f + a2[r] * (1.f - s2));   // gW3 * silu'(a2)
    }
    float dh1[4] = {0.f, 0.f, 0.f, 0.f};
    #pragma unroll 8
    for (int g = 0; g < 32; ++g) {
        float w = w2[lane * 32 + g];
        #pragma unroll
        for (int r = 0; r < 4; ++r) dh1[r] += __shfl(da2[r], g, 32) * w;
    }
    float* o = d1ws + ((size_t)k * BATCH + b0) * 32 + lane;
    #pragma unroll
    for (int r = 0; r < 4; ++r) {
        float da1 = dh1[r] * s1[r] * (1.f + a1[r] * (1.f - s1[r]));  // silu'(a1)
        o[r * 32] = da1;
    }
}

// ---- K2 (MFMA): out[:, 0:2048] = -(z8 @ W[7-k]  +  d1_k @ gW1[k]^T) -----------
// M=8192, N=2048, K=256+32. Block tile 128x128, 4 waves in 2x2, 64x64 each.
// LDS swizzle: 16B chunk c(row,q) = (row&15) + 16*q + 64*(row>>4); wave frag
// read is lane-linear ds_read_b128 (conflict-free).
__global__ __launch_bounds__(256) void k_gemm_lo(
    const float* __restrict__ z, const float* __restrict__ d1,
    const unsigned short* __restrict__ WTb, const unsigned short* __restrict__ gW1b,
    float* __restrict__ out) {
    __shared__ uint4 As4[512];   // 128 rows x 32 k (bf16) = 8 KB
    __shared__ uint4 Bs4[512];   // 128 cols x 32 k (bf16) = 8 KB

    int t = threadIdx.x;
    int lane = t & 63;
    int w = t >> 6;
    int wr = w >> 1, wc = w & 1;
    int b0 = blockIdx.y * 128;
    int n0 = blockIdx.x * 128;
    int k  = n0 >> 8;            // block index 0..7
    int jb = n0 & 255;           // 0 or 128

    const float* Amain = z + (size_t)b0 * ZDIM + 2048;
    const float* Aext  = d1 + ((size_t)k * BATCH + b0) * 32;
    const unsigned short* Bmain = WTb + (size_t)(7 - k) * 65536 + (size_t)jb * 256;
    const unsigned short* Bext  = gW1b + ((size_t)k * 256 + jb) * 32;

    int mq_m = t >> 2;           // base row for staging (pass adds 64)
    int q    = t & 3;

    f32x4 acc[4][4];
    #pragma unroll
    for (int i = 0; i < 4; ++i)
        #pragma unroll
        for (int j = 0; j < 4; ++j) acc[i][j] = (f32x4){0.f, 0.f, 0.f, 0.f};

    for (int c = 0; c < 9; ++c) {
        int kb = c * 32;
        float4 fa[2][2];
        uint4 bu[2];
        #pragma unroll
        for (int pp = 0; pp < 2; ++pp) {
            int m = mq_m + 64 * pp;
            const float* as = (c < 8) ? (Amain + (size_t)m * ZDIM + kb + q * 8)
                                      : (Aext + (size_t)m * 32 + q * 8);
            fa[pp][0] = *(const float4*)(as);
            fa[pp][1] = *(const float4*)(as + 4);
            const unsigned short* bs = (c < 8) ? (Bmain + (size_t)m * 256 + kb + q * 8)
                                               : (Bext + (size_t)m * 32 + q * 8);
            bu[pp] = *(const uint4*)(bs);
        }
        __syncthreads();
        #pragma unroll
        for (int pp = 0; pp < 2; ++pp) {
            int m = mq_m + 64 * pp;
            int ci = (m & 15) + 16 * q + 64 * (m >> 4);
            As4[ci] = pack8(fa[pp][0], fa[pp][1]);
            Bs4[ci] = bu[pp];
        }
        __syncthreads();
        bf16x8 af[4], bf[4];
        #pragma unroll
        for (int i = 0; i < 4; ++i) af[i] = __builtin_bit_cast(bf16x8, As4[lane + (wr * 4 + i) * 64]);
        #pragma unroll
        for (int j = 0; j < 4; ++j) bf[j] = __builtin_bit_cast(bf16x8, Bs4[lane + (wc * 4 + j) * 64]);
        #pragma unroll
        for (int i = 0; i < 4; ++i)
            #pragma unroll
            for (int j = 0; j < 4; ++j)
                acc[i][j] = __builtin_amdgcn_mfma_f32_16x16x32_bf16(af[i], bf[j], acc[i][j], 0, 0, 0);
    }

    int rquad = lane >> 4;
    int cidx  = lane & 15;
    #pragma unroll
    for (int i = 0; i < 4; ++i) {
        #pragma unroll
        for (int j = 0; j < 4; ++j) {
            float* o = out + (size_t)(b0 + wr * 64 + i * 16 + rquad * 4) * ZDIM
                     + (k * 256 + jb + wc * 64 + j * 16 + cidx);
            #pragma unroll
            for (int r = 0; r < 4; ++r)
                o[(size_t)r * ZDIM] = -acc[i][j][r];
        }
    }
}

// ---- K3 (MFMA): out[:, 2048:] = -(sum_m x_m @ W[7-m]^T + d1_8 @ gW1[8]^T) -----
// M=8192, N=256, K=2048+32. Block tile 128x64, 4 waves stacked (32x64 each).
__global__ __launch_bounds__(256) void k_gemm_hi(
    const float* __restrict__ z, const float* __restrict__ d1,
    const unsigned short* __restrict__ Wb, const unsigned short* __restrict__ gW1b,
    float* __restrict__ out) {
    __shared__ uint4 As4[512];   // 128 rows x 32 k = 8 KB
    __shared__ uint4 Bs4[256];   // 64 cols x 32 k = 4 KB

    int t = threadIdx.x;
    int lane = t & 63;
    int w = t >> 6;              // wave 0..3, rows w*32..w*32+31
    int b0 = blockIdx.y * 128;
    int i0 = blockIdx.x * 64;    // output col offset within hi region

    const float* Amain = z + (size_t)b0 * ZDIM;
    const float* Aext  = d1 + ((size_t)8 * BATCH + b0) * 32;
    const unsigned short* Bext = gW1b + (size_t)(8 * 256 + i0) * 32;

    int mq_m = t >> 2;
    int q    = t & 3;

    f32x4 acc[2][4];
    #pragma unroll
    for (int i = 0; i < 2; ++i)
        #pragma unroll
        for (int j = 0; j < 4; ++j) acc[i][j] = (f32x4){0.f, 0.f, 0.f, 0.f};

    for (int c = 0; c < 65; ++c) {
        int kb = c * 32;
        float4 fa[2][2];
        #pragma unroll
        for (int pp = 0; pp < 2; ++pp) {
            int m = mq_m + 64 * pp;
            const float* as = (c < 64) ? (Amain + (size_t)m * ZDIM + kb + q * 8)
                                       : (Aext + (size_t)m * 32 + q * 8);
            fa[pp][0] = *(const float4*)(as);
            fa[pp][1] = *(const float4*)(as + 4);
        }
        // B: 256 chunks, one per thread. n = cols (Wb row i0+n), k = j within lag.
        int bn = t >> 2;
        uint4 bu;
        if (c < 64) {
            int lag = c >> 3;
            int j0  = kb & 255;
            bu = *(const uint4*)(Wb + (size_t)(7 - lag) * 65536 + (size_t)(i0 + bn) * 256 + j0 + q * 8);
        } else {
            bu = *(const uint4*)(Bext + (size_t)bn * 32 + q * 8);
        }
        __syncthreads();
        #pragma unroll
        for (int pp = 0; pp < 2; ++pp) {
            int m = mq_m + 64 * pp;
            As4[(m & 15) + 16 * q + 64 * (m >> 4)] = pack8(fa[pp][0], fa[pp][1]);
        }
        Bs4[(bn & 15) + 16 * q + 64 * (bn >> 4)] = bu;
        __syncthreads();
        bf16x8 af[2], bf[4];
        #pragma unroll
        for (int i = 0; i < 2; ++i) af[i] = __builtin_bit_cast(bf16x8, As4[lane + (w * 2 + i) * 64]);
        #pragma unroll
        for (int j = 0; j < 4; ++j) bf[j] = __builtin_bit_cast(bf16x8, Bs4[lane + j * 64]);
        #pragma unroll
        for (int i = 0; i < 2; ++i)
            #pragma unroll
            for (int j = 0; j < 4; ++j)
                acc[i][j] = __builtin_amdgcn_mfma_f32_16x16x32_bf16(af[i], bf[j], acc[i][j], 0, 0, 0);
    }

    int rquad = lane >> 4;
    int cidx  = lane & 15;
    #pragma unroll
    for (int i = 0; i < 2; ++i) {
        #pragma unroll
        for (int j = 0; j < 4; ++j) {
            float* o = out + (size_t)(b0 + w * 32 + i * 16 + rquad * 4) * ZDIM
                     + (2048 + i0 + j * 16 + cidx);
            #pragma unroll
            for (int r = 0; r < 4; ++r)
                o[(size_t)r * ZDIM] = -acc[i][j][r];
        }
    }
}

extern "C" void kernel_launch(void* const* d_in, const int* in_sizes, int n_in,
                              void* d_out, int out_size, void* d_ws, size_t ws_size,
                              hipStream_t stream) {
    const float* z   = (const float*)d_in[0];
    const float* gW1 = (const float*)d_in[1];
    const float* gb1 = (const float*)d_in[2];
    const float* gW2 = (const float*)d_in[3];
    const float* gb2 = (const float*)d_in[4];
    const float* gW3 = (const float*)d_in[5];
    // d_in[6] = gb3: constant, no grad
    const float* W   = (const float*)d_in[7];
    float* out = (float*)d_out;

    float* ws = (float*)d_ws;
    float*          d1ws = ws;                                  // 2359296 f32 (9.4 MB)
    float*          g1T  = ws + 2359296;                        // 73728 f32
    unsigned short* Wb   = (unsigned short*)(ws + 2359296 + 73728);  // 524288 bf16
    unsigned short* WTb  = Wb + 524288;                         // 524288 bf16
    unsigned short* gW1b = WTb + 524288;                        // 73728 bf16  (~11.9 MB total)

    k_pack<<<dim3(8, 8, 9), 256, 0, stream>>>(W, gW1, Wb, WTb, gW1b, g1T);
    k_mlp_d1<<<2304, 256, 0, stream>>>(z, g1T, gb1, gW2, gb2, gW3, d1ws);
    k_gemm_lo<<<dim3(16, 64), 256, 0, stream>>>(z, d1ws, WTb, gW1b, out);
    k_gemm_hi<<<dim3(4, 64), 256, 0, stream>>>(z, d1ws, Wb, gW1b, out);
}

// Round 3
// 243.739 us; speedup vs baseline: 2.1564x; 1.4580x over previous
//
#include <hip/hip_runtime.h>
#include <hip/hip_bf16.h>
#include <math.h>

// Problem constants
#define BATCH 8192
#define NB 9
#define NN 256
#define PMAX 8
#define HID 32
#define ZDIM 2304   // NB*NN

typedef short bf16x8 __attribute__((ext_vector_type(8)));   // 8 bf16 in 4 VGPRs
typedef float f32x4 __attribute__((ext_vector_type(4)));    // MFMA accumulator

static __device__ inline unsigned short f2bf(float f) {
    __hip_bfloat16 h = __float2bfloat16(f);
    return *reinterpret_cast<unsigned short*>(&h);
}

static __device__ inline uint4 pack8(float4 a, float4 b) {
    uint4 u;
    u.x = (unsigned)f2bf(a.x) | ((unsigned)f2bf(a.y) << 16);
    u.y = (unsigned)f2bf(a.z) | ((unsigned)f2bf(a.w) << 16);
    u.z = (unsigned)f2bf(b.x) | ((unsigned)f2bf(b.y) << 16);
    u.w = (unsigned)f2bf(b.z) | ((unsigned)f2bf(b.w) << 16);
    return u;
}

// ---------------- K0: pack weights to bf16 ------------------------------------
// z<8: W[r] 32x32 tiles -> Wb natural bf16, WTb transposed bf16.
// z==8: gW1 -> gW1b (bf16 [k][n][h]) and g1Tb (bf16 transposed [k][h][n]).
__global__ __launch_bounds__(256) void k_pack(
    const float* __restrict__ W, const float* __restrict__ gW1,
    unsigned short* __restrict__ Wb, unsigned short* __restrict__ WTb,
    unsigned short* __restrict__ gW1b, unsigned short* __restrict__ g1Tb) {
    int r = blockIdx.z;
    int t = threadIdx.x;
    if (r < 8) {
        __shared__ float tt[32][33];
        int i0 = blockIdx.y * 32;
        int j0 = blockIdx.x * 32;
        int tx = t & 31;
        int ty = t >> 5;
        const float* src = W + (size_t)r * 65536;
        #pragma unroll
        for (int s = 0; s < 32; s += 8) {
            float v = src[(size_t)(i0 + ty + s) * 256 + (j0 + tx)];
            tt[ty + s][tx] = v;
            Wb[(size_t)r * 65536 + (size_t)(i0 + ty + s) * 256 + (j0 + tx)] = f2bf(v);
        }
        __syncthreads();
        #pragma unroll
        for (int s = 0; s < 32; s += 8)
            WTb[(size_t)r * 65536 + (size_t)(j0 + ty + s) * 256 + (i0 + tx)] = f2bf(tt[tx][ty + s]);
    } else {
        int tg = (blockIdx.y * 8 + blockIdx.x) * 256 + t;       // 0..16383
        for (int e = tg; e < 73728; e += 16384) {
            float v = gW1[e];
            unsigned short b = f2bf(v);
            gW1b[e] = b;
            int k = e >> 13, n = (e >> 5) & 255, h = e & 31;
            g1Tb[(size_t)(k * 32 + h) * 256 + n] = b;
        }
    }
}

// -------------------- K1 (MFMA): d1[k][b][h] = silu'(a1) * upstream -----------
// One WG = 128 batch rows of one block k. 4 waves, wave w -> rows w*32..+31.
// Layer1: M=128,N=32,K=256 mfma. Layers 2/3: K=32 mfma via LDS round-trips.
__global__ __launch_bounds__(256) void k_mlp(
    const float* __restrict__ z, const unsigned short* __restrict__ g1Tb,
    const float* __restrict__ gb1, const float* __restrict__ gW2,
    const float* __restrict__ gb2, const float* __restrict__ gW3,
    float* __restrict__ d1ws) {
    __shared__ uint4 As4[512];    // 128 rows x 32 k bf16 (reused for h1 / da2)
    __shared__ uint4 Bw[1024];    // gW1^T block: 32 h x 256 n bf16, 8 chunk-regions
    __shared__ uint4 W2Ts4[128];  // W2^T [g][h] bf16 (fragment layout)
    __shared__ uint4 W2Ns4[128];  // W2 natural [h][g] bf16 (fragment layout)

    int t = threadIdx.x;
    int lane = t & 63;
    int w = t >> 6;
    int k = blockIdx.y;
    int b0 = blockIdx.x * 128;

    // ---- stage B (gW1^T) and W2 tiles ----
    const unsigned short* bsrc = g1Tb + (size_t)k * 8192;
    for (int e = t; e < 1024; e += 256) {
        int h = e >> 5;
        int rest = e & 31;
        int c = rest >> 2, q = rest & 3;
        Bw[c * 128 + (h & 15) + 16 * q + 64 * (h >> 4)] =
            *(const uint4*)(bsrc + (size_t)h * 256 + c * 32 + q * 8);
    }
    const float* gw2 = gW2 + (size_t)k * 1024;
    unsigned short* w2t = (unsigned short*)W2Ts4;
    unsigned short* w2n = (unsigned short*)W2Ns4;
    for (int e = t; e < 1024; e += 256) {
        int n = e >> 5, kk = e & 31;
        int q = kk >> 3, jj = kk & 7;
        int ci = (n & 15) + 16 * q + 64 * (n >> 4);
        w2t[ci * 8 + jj] = f2bf(gw2[kk * 32 + n]);   // W2T[g=n][h=kk]
        w2n[ci * 8 + jj] = f2bf(gw2[n * 32 + kk]);   // W2N[h=n][g=kk]
    }

    int mq_m = t >> 2;
    int q = t & 3;

    // ---- layer-1 GEMM: acc1 = z_k @ gW1[k] ----
    f32x4 acc1[2][2];
    #pragma unroll
    for (int i = 0; i < 2; ++i)
        #pragma unroll
        for (int j = 0; j < 2; ++j) acc1[i][j] = (f32x4){0.f, 0.f, 0.f, 0.f};

    for (int c = 0; c < 8; ++c) {
        float4 fa[2][2];
        #pragma unroll
        for (int pp = 0; pp < 2; ++pp) {
            int m = mq_m + 64 * pp;
            const float* as = z + (size_t)(b0 + m) * ZDIM + k * 256 + c * 32 + q * 8;
            fa[pp][0] = *(const float4*)(as);
            fa[pp][1] = *(const float4*)(as + 4);
        }
        __syncthreads();
        #pragma unroll
        for (int pp = 0; pp < 2; ++pp) {
            int m = mq_m + 64 * pp;
            As4[(m & 15) + 16 * q + 64 * (m >> 4)] = pack8(fa[pp][0], fa[pp][1]);
        }
        __syncthreads();
        bf16x8 af[2], bfr[2];
        #pragma unroll
        for (int i = 0; i < 2; ++i) af[i] = __builtin_bit_cast(bf16x8, As4[lane + (w * 2 + i) * 64]);
        #pragma unroll
        for (int j = 0; j < 2; ++j) bfr[j] = __builtin_bit_cast(bf16x8, Bw[c * 128 + lane + j * 64]);
        #pragma unroll
        for (int i = 0; i < 2; ++i)
            #pragma unroll
            for (int j = 0; j < 2; ++j)
                acc1[i][j] = __builtin_amdgcn_mfma_f32_16x16x32_bf16(af[i], bfr[j], acc1[i][j], 0, 0, 0);
    }

    // ---- bias + silu; keep silu'(a1); h1 -> LDS (chunk-swizzled bf16) ----
    int cq = lane >> 4;        // C-layout row quad
    int ci16 = lane & 15;      // C-layout col
    float b1v[2], b2v[2], g3v[2];
    #pragma unroll
    for (int j = 0; j < 2; ++j) {
        b1v[j] = gb1[k * 32 + j * 16 + ci16];
        b2v[j] = gb2[k * 32 + j * 16 + ci16];
        g3v[j] = gW3[k * 32 + j * 16 + ci16];
    }
    unsigned short* Hs = (unsigned short*)As4;
    float sp1[2][2][4];
    __syncthreads();           // all stage-1 As4 reads done
    #pragma unroll
    for (int i = 0; i < 2; ++i)
        #pragma unroll
        for (int j = 0; j < 2; ++j)
            #pragma unroll
            for (int r = 0; r < 4; ++r) {
                float a1 = acc1[i][j][r] + b1v[j];
                float s1 = 1.f / (1.f + __expf(-a1));
                sp1[i][j][r] = s1 * (1.f + a1 * (1.f - s1));
                int row = w * 32 + i * 16 + cq * 4 + r;
                int col = j * 16 + ci16;
                int chunk = (row & 15) + 16 * (col >> 3) + 64 * (row >> 4);
                Hs[chunk * 8 + (col & 7)] = f2bf(a1 * s1);
            }
    __syncthreads();

    // ---- layer-2: a2 = h1 @ W2 ----
    bf16x8 af2[2], wf[2];
    #pragma unroll
    for (int i = 0; i < 2; ++i) af2[i] = __builtin_bit_cast(bf16x8, As4[lane + (w * 2 + i) * 64]);
    #pragma unroll
    for (int j = 0; j < 2; ++j) wf[j] = __builtin_bit_cast(bf16x8, W2Ts4[lane + j * 64]);
    f32x4 acc2[2][2];
    #pragma unroll
    for (int i = 0; i < 2; ++i)
        #pragma unroll
        for (int j = 0; j < 2; ++j) {
            acc2[i][j] = (f32x4){0.f, 0.f, 0.f, 0.f};
            acc2[i][j] = __builtin_amdgcn_mfma_f32_16x16x32_bf16(af2[i], wf[j], acc2[i][j], 0, 0, 0);
        }

    // ---- da2 = gW3 * silu'(a2) -> LDS ----
    __syncthreads();           // h1 reads done
    #pragma unroll
    for (int i = 0; i < 2; ++i)
        #pragma unroll
        for (int j = 0; j < 2; ++j)
            #pragma unroll
            for (int r = 0; r < 4; ++r) {
                float a2 = acc2[i][j][r] + b2v[j];
                float s2 = 1.f / (1.f + __expf(-a2));
                float da2 = g3v[j] * s2 * (1.f + a2 * (1.f - s2));
                int row = w * 32 + i * 16 + cq * 4 + r;
                int col = j * 16 + ci16;
                int chunk = (row & 15) + 16 * (col >> 3) + 64 * (row >> 4);
                Hs[chunk * 8 + (col & 7)] = f2bf(da2);
            }
    __syncthreads();

    // ---- layer-3: dh1 = da2 @ W2^T; d1 = dh1 * silu'(a1) -> global ----
    bf16x8 af3[2], wg[2];
    #pragma unroll
    for (int i = 0; i < 2; ++i) af3[i] = __builtin_bit_cast(bf16x8, As4[lane + (w * 2 + i) * 64]);
    #pragma unroll
    for (int j = 0; j < 2; ++j) wg[j] = __builtin_bit_cast(bf16x8, W2Ns4[lane + j * 64]);
    #pragma unroll
    for (int i = 0; i < 2; ++i)
        #pragma unroll
        for (int j = 0; j < 2; ++j) {
            f32x4 a3 = (f32x4){0.f, 0.f, 0.f, 0.f};
            a3 = __builtin_amdgcn_mfma_f32_16x16x32_bf16(af3[i], wg[j], a3, 0, 0, 0);
            #pragma unroll
            for (int r = 0; r < 4; ++r) {
                int row = w * 32 + i * 16 + cq * 4 + r;
                int col = j * 16 + ci16;
                d1ws[((size_t)k * BATCH + b0 + row) * 32 + col] = a3[r] * sp1[i][j][r];
            }
        }
}

// ---- K2 (MFMA): out[:, 0:2048] = -(z8 @ W[7-k]  +  d1_k @ gW1[k]^T) -----------
__global__ __launch_bounds__(256) void k_gemm_lo(
    const float* __restrict__ z, const float* __restrict__ d1,
    const unsigned short* __restrict__ WTb, const unsigned short* __restrict__ gW1b,
    float* __restrict__ out) {
    __shared__ uint4 As4[512];   // 128 rows x 32 k (bf16) = 8 KB
    __shared__ uint4 Bs4[512];   // 128 cols x 32 k (bf16) = 8 KB

    int t = threadIdx.x;
    int lane = t & 63;
    int w = t >> 6;
    int wr = w >> 1, wc = w & 1;
    int b0 = blockIdx.y * 128;
    int n0 = blockIdx.x * 128;
    int k  = n0 >> 8;            // block index 0..7
    int jb = n0 & 255;           // 0 or 128

    const float* Amain = z + (size_t)b0 * ZDIM + 2048;
    const float* Aext  = d1 + ((size_t)k * BATCH + b0) * 32;
    const unsigned short* Bmain = WTb + (size_t)(7 - k) * 65536 + (size_t)jb * 256;
    const unsigned short* Bext  = gW1b + ((size_t)k * 256 + jb) * 32;

    int mq_m = t >> 2;
    int q    = t & 3;

    f32x4 acc[4][4];
    #pragma unroll
    for (int i = 0; i < 4; ++i)
        #pragma unroll
        for (int j = 0; j < 4; ++j) acc[i][j] = (f32x4){0.f, 0.f, 0.f, 0.f};

    for (int c = 0; c < 9; ++c) {
        int kb = c * 32;
        float4 fa[2][2];
        uint4 bu[2];
        #pragma unroll
        for (int pp = 0; pp < 2; ++pp) {
            int m = mq_m + 64 * pp;
            const float* as = (c < 8) ? (Amain + (size_t)m * ZDIM + kb + q * 8)
                                      : (Aext + (size_t)m * 32 + q * 8);
            fa[pp][0] = *(const float4*)(as);
            fa[pp][1] = *(const float4*)(as + 4);
            const unsigned short* bs = (c < 8) ? (Bmain + (size_t)m * 256 + kb + q * 8)
                                               : (Bext + (size_t)m * 32 + q * 8);
            bu[pp] = *(const uint4*)(bs);
        }
        __syncthreads();
        #pragma unroll
        for (int pp = 0; pp < 2; ++pp) {
            int m = mq_m + 64 * pp;
            int ci = (m & 15) + 16 * q + 64 * (m >> 4);
            As4[ci] = pack8(fa[pp][0], fa[pp][1]);
            Bs4[ci] = bu[pp];
        }
        __syncthreads();
        bf16x8 af[4], bf[4];
        #pragma unroll
        for (int i = 0; i < 4; ++i) af[i] = __builtin_bit_cast(bf16x8, As4[lane + (wr * 4 + i) * 64]);
        #pragma unroll
        for (int j = 0; j < 4; ++j) bf[j] = __builtin_bit_cast(bf16x8, Bs4[lane + (wc * 4 + j) * 64]);
        #pragma unroll
        for (int i = 0; i < 4; ++i)
            #pragma unroll
            for (int j = 0; j < 4; ++j)
                acc[i][j] = __builtin_amdgcn_mfma_f32_16x16x32_bf16(af[i], bf[j], acc[i][j], 0, 0, 0);
    }

    int rquad = lane >> 4;
    int cidx  = lane & 15;
    #pragma unroll
    for (int i = 0; i < 4; ++i) {
        #pragma unroll
        for (int j = 0; j < 4; ++j) {
            float* o = out + (size_t)(b0 + wr * 64 + i * 16 + rquad * 4) * ZDIM
                     + (k * 256 + jb + wc * 64 + j * 16 + cidx);
            #pragma unroll
            for (int r = 0; r < 4; ++r)
                o[(size_t)r * ZDIM] = -acc[i][j][r];
        }
    }
}

// ---- K3 (MFMA): out[:, 2048:] = -(sum_m x_m @ W[7-m]^T + d1_8 @ gW1[8]^T) -----
__global__ __launch_bounds__(256) void k_gemm_hi(
    const float* __restrict__ z, const float* __restrict__ d1,
    const unsigned short* __restrict__ Wb, const unsigned short* __restrict__ gW1b,
    float* __restrict__ out) {
    __shared__ uint4 As4[512];   // 128 rows x 32 k = 8 KB
    __shared__ uint4 Bs4[256];   // 64 cols x 32 k = 4 KB

    int t = threadIdx.x;
    int lane = t & 63;
    int w = t >> 6;
    int b0 = blockIdx.y * 128;
    int i0 = blockIdx.x * 64;

    const float* Amain = z + (size_t)b0 * ZDIM;
    const float* Aext  = d1 + ((size_t)8 * BATCH + b0) * 32;
    const unsigned short* Bext = gW1b + (size_t)(8 * 256 + i0) * 32;

    int mq_m = t >> 2;
    int q    = t & 3;

    f32x4 acc[2][4];
    #pragma unroll
    for (int i = 0; i < 2; ++i)
        #pragma unroll
        for (int j = 0; j < 4; ++j) acc[i][j] = (f32x4){0.f, 0.f, 0.f, 0.f};

    for (int c = 0; c < 65; ++c) {
        int kb = c * 32;
        float4 fa[2][2];
        #pragma unroll
        for (int pp = 0; pp < 2; ++pp) {
            int m = mq_m + 64 * pp;
            const float* as = (c < 64) ? (Amain + (size_t)m * ZDIM + kb + q * 8)
                                       : (Aext + (size_t)m * 32 + q * 8);
            fa[pp][0] = *(const float4*)(as);
            fa[pp][1] = *(const float4*)(as + 4);
        }
        int bn = t >> 2;
        uint4 bu;
        if (c < 64) {
            int lag = c >> 3;
            int j0  = kb & 255;
            bu = *(const uint4*)(Wb + (size_t)(7 - lag) * 65536 + (size_t)(i0 + bn) * 256 + j0 + q * 8);
        } else {
            bu = *(const uint4*)(Bext + (size_t)bn * 32 + q * 8);
        }
        __syncthreads();
        #pragma unroll
        for (int pp = 0; pp < 2; ++pp) {
            int m = mq_m + 64 * pp;
            As4[(m & 15) + 16 * q + 64 * (m >> 4)] = pack8(fa[pp][0], fa[pp][1]);
        }
        Bs4[(bn & 15) + 16 * q + 64 * (bn >> 4)] = bu;
        __syncthreads();
        bf16x8 af[2], bf[4];
        #pragma unroll
        for (int i = 0; i < 2; ++i) af[i] = __builtin_bit_cast(bf16x8, As4[lane + (w * 2 + i) * 64]);
        #pragma unroll
        for (int j = 0; j < 4; ++j) bf[j] = __builtin_bit_cast(bf16x8, Bs4[lane + j * 64]);
        #pragma unroll
        for (int i = 0; i < 2; ++i)
            #pragma unroll
            for (int j = 0; j < 4; ++j)
                acc[i][j] = __builtin_amdgcn_mfma_f32_16x16x32_bf16(af[i], bf[j], acc[i][j], 0, 0, 0);
    }

    int rquad = lane >> 4;
    int cidx  = lane & 15;
    #pragma unroll
    for (int i = 0; i < 2; ++i) {
        #pragma unroll
        for (int j = 0; j < 4; ++j) {
            float* o = out + (size_t)(b0 + w * 32 + i * 16 + rquad * 4) * ZDIM
                     + (2048 + i0 + j * 16 + cidx);
            #pragma unroll
            for (int r = 0; r < 4; ++r)
                o[(size_t)r * ZDIM] = -acc[i][j][r];
        }
    }
}

extern "C" void kernel_launch(void* const* d_in, const int* in_sizes, int n_in,
                              void* d_out, int out_size, void* d_ws, size_t ws_size,
                              hipStream_t stream) {
    const float* z   = (const float*)d_in[0];
    const float* gW1 = (const float*)d_in[1];
    const float* gb1 = (const float*)d_in[2];
    const float* gW2 = (const float*)d_in[3];
    const float* gb2 = (const float*)d_in[4];
    const float* gW3 = (const float*)d_in[5];
    // d_in[6] = gb3: constant, no grad
    const float* W   = (const float*)d_in[7];
    float* out = (float*)d_out;

    float* ws = (float*)d_ws;
    float*          d1ws = ws;                               // 2359296 f32 (9.4 MB)
    unsigned short* Wb   = (unsigned short*)(ws + 2359296);  // 524288 bf16
    unsigned short* WTb  = Wb + 524288;                      // 524288 bf16
    unsigned short* gW1b = WTb + 524288;                     // 73728 bf16
    unsigned short* g1Tb = gW1b + 73728;                     // 73728 bf16 (~11.8 MB total)

    k_pack<<<dim3(8, 8, 9), 256, 0, stream>>>(W, gW1, Wb, WTb, gW1b, g1Tb);
    k_mlp<<<dim3(64, 9), 256, 0, stream>>>(z, g1Tb, gb1, gW2, gb2, gW3, d1ws);
    k_gemm_lo<<<dim3(16, 64), 256, 0, stream>>>(z, d1ws, WTb, gW1b, out);
    k_gemm_hi<<<dim3(4, 64), 256, 0, stream>>>(z, d1ws, Wb, gW1b, out);
}